// Round 2
// baseline (596.418 us; speedup 1.0000x reference)
//
#include <hip/hip_runtime.h>

// GeneDynamics: out = -x + (A @ x^2) / (x^2 + 1)
// A: [16384,16384] fp32 (1.07 GB, streamed once -> HBM-bound, target ~171us)
// x: [16384,16] fp32, t: scalar int (unused)

#define NN 16384
#define DIM 16
#define RB 512                 // rows per block
#define TPB 256
#define KSPLIT 32              // K-split factor (partials via atomicAdd)
#define KRANGE (NN / KSPLIT)   // 512
#define KC 16                  // K per LDS chunk
#define PAD 17                 // odd stride -> conflict-free per-row ds_read_b32
#define NRB (NN / RB)          // 32 row-blocks

__global__ __launch_bounds__(256) void init_out_kernel(const float* __restrict__ x,
                                                       float* __restrict__ out) {
    int i = blockIdx.x * 256 + threadIdx.x;           // 65536 float4s
    float4 v = reinterpret_cast<const float4*>(x)[i];
    reinterpret_cast<float4*>(out)[i] = make_float4(-v.x, -v.y, -v.z, -v.w);
}

__global__ __launch_bounds__(TPB, 4) void agg_kernel(const float* __restrict__ A,
                                                     const float* __restrict__ x,
                                                     float* __restrict__ out) {
    __shared__ float a_t[RB * PAD];      // 512*17*4 = 34816 B
    __shared__ float xh_t[KC * DIM];     // 1024 B   (x^2 chunk)

    const int tid = threadIdx.x;
    const int rb  = blockIdx.x & (NRB - 1);   // 0..31 row-block
    const int ks  = blockIdx.x / NRB;         // 0..31 k-split
    const int r0  = rb * RB;
    const int k0  = ks * KRANGE;

    float4 acc0[4], acc1[4];                  // 2 rows x 16 dims per thread
    #pragma unroll
    for (int v = 0; v < 4; ++v) {
        acc0[v] = make_float4(0.f, 0.f, 0.f, 0.f);
        acc1[v] = make_float4(0.f, 0.f, 0.f, 0.f);
    }

    const int lrow = tid >> 2;     // 0..63
    const int lc4  = tid & 3;      // 0..3 (float4 column within 16-wide row)

    const float* Ab0 = A + (size_t)(r0 + lrow) * NN + k0 + (lc4 << 2);

    for (int c = 0; c < KRANGE; c += KC) {
        __syncthreads();
        // ---- stage A tile: 512 rows x 16 cols, coalesced float4 loads ----
        #pragma unroll
        for (int j = 0; j < 8; ++j) {
            float4 v = *reinterpret_cast<const float4*>(Ab0 + (size_t)(j * 64) * NN + c);
            int b = (lrow + j * 64) * PAD + (lc4 << 2);
            a_t[b]     = v.x;
            a_t[b + 1] = v.y;
            a_t[b + 2] = v.z;
            a_t[b + 3] = v.w;
        }
        // ---- stage x^2 chunk: 16 k-rows x 16 dims = 256 elems, 1/thread ----
        {
            float xv = x[(size_t)(k0 + c) * DIM + tid];
            xh_t[tid] = xv * xv;
        }
        __syncthreads();
        // ---- compute: per k: 2 ds_read_b32 (A) + 4 broadcast ds_read_b128 (xh) + 32 FMA ----
        #pragma unroll
        for (int k = 0; k < KC; ++k) {
            float a0 = a_t[tid * PAD + k];
            float a1 = a_t[(tid + 256) * PAD + k];
            const float4* xr = reinterpret_cast<const float4*>(&xh_t[k * DIM]);
            #pragma unroll
            for (int v = 0; v < 4; ++v) {
                float4 q = xr[v];
                acc0[v].x += a0 * q.x; acc0[v].y += a0 * q.y;
                acc0[v].z += a0 * q.z; acc0[v].w += a0 * q.w;
                acc1[v].x += a1 * q.x; acc1[v].y += a1 * q.y;
                acc1[v].z += a1 * q.z; acc1[v].w += a1 * q.w;
            }
        }
    }

    // ---- epilogue: out += partial_agg / (x^2 + 1)  (linear in agg -> split-K safe) ----
    #pragma unroll
    for (int h = 0; h < 2; ++h) {
        int r = r0 + tid + h * 256;
        const float4* xr4 = reinterpret_cast<const float4*>(x + (size_t)r * DIM);
        float* orow = out + (size_t)r * DIM;
        #pragma unroll
        for (int v = 0; v < 4; ++v) {
            float4 xv = xr4[v];
            float4 a = h ? acc1[v] : acc0[v];
            atomicAdd(&orow[(v << 2) + 0], a.x / (xv.x * xv.x + 1.0f));
            atomicAdd(&orow[(v << 2) + 1], a.y / (xv.y * xv.y + 1.0f));
            atomicAdd(&orow[(v << 2) + 2], a.z / (xv.z * xv.z + 1.0f));
            atomicAdd(&orow[(v << 2) + 3], a.w / (xv.w * xv.w + 1.0f));
        }
    }
}

extern "C" void kernel_launch(void* const* d_in, const int* in_sizes, int n_in,
                              void* d_out, int out_size, void* d_ws, size_t ws_size,
                              hipStream_t stream) {
    const float* A = (const float*)d_in[0];
    const float* x = (const float*)d_in[1];
    // d_in[2] = t (unused)
    float* out = (float*)d_out;

    // out = -x  (also clears poison every call)
    init_out_kernel<<<(NN * DIM / 4) / 256, 256, 0, stream>>>(x, out);
    // out += (A @ x^2)/(x^2+1), split-K atomic accumulate
    agg_kernel<<<NRB * KSPLIT, TPB, 0, stream>>>(A, x, out);
}